// Round 2
// baseline (9106.306 us; speedup 1.0000x reference)
//
#include <hip/hip_runtime.h>

#define Bsz 512
#define Lsz 30
#define Hsz 1024
#define Tsz 30
#define NG  3072

// ---------------- init: h0 = mean_L(input_hidden), valid mask, flag=0 ----------
__global__ __launch_bounds__(256) void k_init(
    const float* __restrict__ ih, const int* __restrict__ pos,
    float* __restrict__ h, unsigned int* __restrict__ flag,
    unsigned int* __restrict__ valid)
{
  const int b = blockIdx.x;
  const float* base = ih + (size_t)b * Lsz * Hsz;
  #pragma unroll
  for (int i = 0; i < 4; ++i) {
    const int c = threadIdx.x + 256 * i;
    float s = 0.f;
    for (int l = 0; l < Lsz; ++l) s += base[l * Hsz + c];
    h[(size_t)b * Hsz + c] = s / 30.0f;
  }
  if (threadIdx.x == 0) {
    int ss = 0;
    for (int l = 0; l < Lsz; ++l) ss += (pos[b * Lsz + l] != -1) ? 1 : 0;
    valid[b] = (ss >= 32) ? 0xFFFFFFFFu : ((1u << ss) - 1u);
    flag[b]  = 0u;
  }
}

// ---------------- C[M,N] = A[M,K] @ B[N,K]^T (+ bias), fp32 --------------------
// A row stride configurable (0 broadcasts one row, used for S at t=0).
// tile 64x64, K-step 16, 256 threads, 4x4 micro-tile per thread.
__global__ __launch_bounds__(256) void k_gemm_nt(
    const float* __restrict__ A, long strideA,
    const float* __restrict__ B,
    const float* __restrict__ bias,
    float* __restrict__ C, int N)
{
  __shared__ float As[64][17];
  __shared__ float Bs[64][17];
  const int tid = threadIdx.x;
  const int tx = tid & 15, ty = tid >> 4;
  const int bn = blockIdx.x * 64, bm = blockIdx.y * 64;

  float acc[4][4] = {};

  for (int k0 = 0; k0 < Hsz; k0 += 16) {
    #pragma unroll
    for (int e = 0; e < 4; ++e) {
      const int el = tid + 256 * e;
      const int m = el >> 4, kk = el & 15;
      As[m][kk] = A[(size_t)(bm + m) * strideA + k0 + kk];
      Bs[m][kk] = B[(size_t)(bn + m) * Hsz + k0 + kk];
    }
    __syncthreads();
    #pragma unroll
    for (int kk = 0; kk < 16; ++kk) {
      float a[4], bb[4];
      #pragma unroll
      for (int i = 0; i < 4; ++i) a[i] = As[ty * 4 + i][kk];
      #pragma unroll
      for (int j = 0; j < 4; ++j) bb[j] = Bs[tx * 4 + j][kk];
      #pragma unroll
      for (int i = 0; i < 4; ++i)
        #pragma unroll
        for (int j = 0; j < 4; ++j) acc[i][j] = fmaf(a[i], bb[j], acc[i][j]);
    }
    __syncthreads();
  }

  #pragma unroll
  for (int i = 0; i < 4; ++i) {
    const int m = bm + ty * 4 + i;
    #pragma unroll
    for (int j = 0; j < 4; ++j) {
      const int n = bn + tx * 4 + j;
      float v = acc[i][j];
      if (bias) v += bias[n];
      C[(size_t)m * N + n] = v;
    }
  }
}

// ---------------- GRU combine: h_new from gi, gh, biases -----------------------
__global__ __launch_bounds__(256) void k_combine(
    const float* __restrict__ gi, const float* __restrict__ gh,
    const float* __restrict__ bih, const float* __restrict__ bhh,
    const float* __restrict__ h_in, float* __restrict__ h_out)
{
  const int idx = blockIdx.x * 256 + threadIdx.x;   // 512*1024 total
  const int b = idx >> 10, c = idx & 1023;
  const size_t g = (size_t)b * NG;
  const float ir  = gi[g + c]           + bih[c];
  const float iz  = gi[g + Hsz + c]     + bih[Hsz + c];
  const float inn = gi[g + 2*Hsz + c]   + bih[2*Hsz + c];
  const float hr  = gh[g + c]           + bhh[c];
  const float hz  = gh[g + Hsz + c]     + bhh[Hsz + c];
  const float hn  = gh[g + 2*Hsz + c]   + bhh[2*Hsz + c];
  const float r = 1.f / (1.f + expf(-(ir + hr)));
  const float z = 1.f / (1.f + expf(-(iz + hz)));
  const float n = tanhf(inn + r * hn);
  h_out[idx] = (1.f - z) * n + z * h_in[idx];
}

// ---------------- attention scores + masked softmax + argmax/flag + outputs ----
__global__ __launch_bounds__(256) void k_attn(
    const float* __restrict__ q, const float* __restrict__ ih,
    unsigned int* __restrict__ flag, const unsigned int* __restrict__ valid,
    float* __restrict__ out, int t)
{
  const int b = blockIdx.x;
  __shared__ float pre_s[32];
  __shared__ float top_s[32];
  const int w = threadIdx.x >> 6;
  const int lane = threadIdx.x & 63;

  // per-lane 16 q elements: [16*lane, 16*lane+16)
  float qr[16];
  const float4* q4 = (const float4*)(q + (size_t)b * Hsz);
  #pragma unroll
  for (int i = 0; i < 4; ++i) {
    const float4 v = q4[lane * 4 + i];
    qr[4*i+0] = v.x; qr[4*i+1] = v.y; qr[4*i+2] = v.z; qr[4*i+3] = v.w;
  }

  for (int l = w; l < Lsz; l += 4) {
    const float4* r4 = (const float4*)(ih + (size_t)b * Lsz * Hsz + (size_t)l * Hsz);
    float s = 0.f;
    #pragma unroll
    for (int i = 0; i < 4; ++i) {
      const float4 v = r4[lane * 4 + i];
      s = fmaf(qr[4*i+0], v.x, s);
      s = fmaf(qr[4*i+1], v.y, s);
      s = fmaf(qr[4*i+2], v.z, s);
      s = fmaf(qr[4*i+3], v.w, s);
    }
    #pragma unroll
    for (int off = 32; off >= 1; off >>= 1) s += __shfl_xor(s, off, 64);
    if (lane == 0) pre_s[l] = s;
  }
  __syncthreads();

  if (threadIdx.x == 0) {
    const unsigned int fl = flag[b];
    const unsigned int ex = fl | ~valid[b];
    float best = -3.4e38f; int am = 0;
    for (int l = 0; l < Lsz; ++l) {
      if (!((ex >> l) & 1u)) { const float v = pre_s[l]; if (v > best) { best = v; am = l; } }
    }
    float sum = 0.f;
    for (int l = 0; l < Lsz; ++l) {
      const float e = ((ex >> l) & 1u) ? 0.f : expf(pre_s[l] - best);
      top_s[l] = e; sum += e;
    }
    const float inv = 1.f / sum;
    for (int l = 0; l < Lsz; ++l) top_s[l] *= inv;
    flag[b] = fl | (1u << am);
  }
  __syncthreads();

  if (threadIdx.x < Lsz) {
    const int l = threadIdx.x;
    out[(size_t)b * (Tsz * Lsz) + t * Lsz + l] = pre_s[l];
    out[(size_t)Bsz * Tsz * Lsz + (size_t)b * (Tsz * Lsz) + t * Lsz + l] = top_s[l];
  }
}

extern "C" void kernel_launch(void* const* d_in, const int* in_sizes, int n_in,
                              void* d_out, int out_size, void* d_ws, size_t ws_size,
                              hipStream_t stream) {
  const float* ih  = (const float*)d_in[0];
  const float* tg  = (const float*)d_in[1];
  const int*   pos = (const int*)d_in[2];
  const float* S   = (const float*)d_in[4];
  const float* wih = (const float*)d_in[5];
  const float* whh = (const float*)d_in[6];
  const float* bih = (const float*)d_in[7];
  const float* bhh = (const float*)d_in[8];
  const float* wlw = (const float*)d_in[9];
  const float* wlb = (const float*)d_in[10];
  float* out = (float*)d_out;

  char* p = (char*)d_ws;
  float* gi  = (float*)p; p += (size_t)Bsz * NG * 4;
  float* gh  = (float*)p; p += (size_t)Bsz * NG * 4;
  float* q   = (float*)p; p += (size_t)Bsz * Hsz * 4;
  float* hf0 = (float*)p; p += (size_t)Bsz * Hsz * 4;
  float* hf1 = (float*)p; p += (size_t)Bsz * Hsz * 4;
  unsigned int* flag  = (unsigned int*)p; p += (size_t)Bsz * 4;
  unsigned int* valid = (unsigned int*)p; p += (size_t)Bsz * 4;

  k_init<<<Bsz, 256, 0, stream>>>(ih, pos, hf0, flag, valid);

  for (int t = 0; t < Tsz; ++t) {
    const float* xsrc = (t == 0) ? S : (tg + (size_t)(t - 1) * Hsz);
    const long xstr = (t == 0) ? 0L : (long)(Tsz * Hsz);
    const float* hin  = (t & 1) ? hf1 : hf0;
    float*       hout = (t & 1) ? hf0 : hf1;

    k_gemm_nt<<<dim3(NG / 64, Bsz / 64), 256, 0, stream>>>(xsrc, xstr, wih, nullptr, gi, NG);
    k_gemm_nt<<<dim3(NG / 64, Bsz / 64), 256, 0, stream>>>(hin, (long)Hsz, whh, nullptr, gh, NG);
    k_combine<<<(Bsz * Hsz) / 256, 256, 0, stream>>>(gi, gh, bih, bhh, hin, hout);
    k_gemm_nt<<<dim3(Hsz / 64, Bsz / 64), 256, 0, stream>>>(hout, (long)Hsz, wlw, wlb, q, Hsz);
    k_attn<<<Bsz, 256, 0, stream>>>(q, ih, flag, valid, out, t);
  }
}

// Round 3
// 4194.860 us; speedup vs baseline: 2.1708x; 2.1708x over previous
//
#include <hip/hip_runtime.h>

#define Bsz 512
#define Lsz 30
#define Hsz 1024
#define Tsz 30

typedef __bf16 bf16x8 __attribute__((ext_vector_type(8)));
typedef float  f32x4  __attribute__((ext_vector_type(4)));

__device__ __forceinline__ float bf2f(unsigned short s) {
  union { unsigned int u; float f; } v; v.u = ((unsigned int)s) << 16; return v.f;
}
__device__ __forceinline__ unsigned short f2bf(float f) {
  union { float f; unsigned int u; } v; v.f = f;
  return (unsigned short)((v.u + 0x7FFFu + ((v.u >> 16) & 1u)) >> 16);
}
__device__ __forceinline__ bf16x8 ld8u(const unsigned short* p) {
  return *reinterpret_cast<const bf16x8*>(p);
}

// ---------------- split fp32 -> (hi, lo) bf16 planes ---------------------------
__global__ __launch_bounds__(256) void k_split(
    const float* __restrict__ src, unsigned short* __restrict__ hi,
    unsigned short* __restrict__ lo, int n4)
{
  const int i = blockIdx.x * 256 + threadIdx.x;
  if (i >= n4) return;
  const float4 v = ((const float4*)src)[i];
  unsigned short h0 = f2bf(v.x), h1 = f2bf(v.y), h2 = f2bf(v.z), h3 = f2bf(v.w);
  unsigned short l0 = f2bf(v.x - bf2f(h0)), l1 = f2bf(v.y - bf2f(h1));
  unsigned short l2 = f2bf(v.z - bf2f(h2)), l3 = f2bf(v.w - bf2f(h3));
  ((ushort4*)hi)[i] = make_ushort4(h0, h1, h2, h3);
  ((ushort4*)lo)[i] = make_ushort4(l0, l1, l2, l3);
}

// ---------------- init: h0 = mean_L(input_hidden) + splits, masks --------------
__global__ __launch_bounds__(256) void k_init(
    const float* __restrict__ ih, const int* __restrict__ pos,
    float* __restrict__ hf, unsigned short* __restrict__ hh,
    unsigned short* __restrict__ hl,
    unsigned int* __restrict__ flag, unsigned int* __restrict__ valid)
{
  const int b = blockIdx.x;
  const float* base = ih + (size_t)b * Lsz * Hsz;
  #pragma unroll
  for (int i = 0; i < 4; ++i) {
    const int c = threadIdx.x + 256 * i;
    float s = 0.f;
    for (int l = 0; l < Lsz; ++l) s += base[l * Hsz + c];
    s /= 30.0f;
    const size_t o = (size_t)b * Hsz + c;
    hf[o] = s;
    const unsigned short h = f2bf(s);
    hh[o] = h; hl[o] = f2bf(s - bf2f(h));
  }
  if (threadIdx.x == 0) {
    int ss = 0;
    for (int l = 0; l < Lsz; ++l) ss += (pos[b * Lsz + l] != -1) ? 1 : 0;
    valid[b] = (ss >= 32) ? 0xFFFFFFFFu : ((1u << ss) - 1u);
    flag[b]  = 0u;
  }
}

// ---------------- fused GRU step: gi + gh 3-pass MFMA + combine ----------------
// grid (32,8), 128 threads (2 waves). Block = 64 rows x 32 cols. Wave = 32x32.
__global__ __launch_bounds__(128) void k_gru(
    const unsigned short* __restrict__ xh, const unsigned short* __restrict__ xl,
    long xstr,
    const float* __restrict__ hf_in,
    const unsigned short* __restrict__ hhi, const unsigned short* __restrict__ hli,
    const unsigned short* __restrict__ wihh, const unsigned short* __restrict__ wihl,
    const unsigned short* __restrict__ whhh, const unsigned short* __restrict__ whhl,
    const float* __restrict__ bih, const float* __restrict__ bhh,
    float* __restrict__ hf_out, unsigned short* __restrict__ hho,
    unsigned short* __restrict__ hlo)
{
  const int nt = blockIdx.x * 32;
  const int mt = blockIdx.y * 64;
  const int w = threadIdx.x >> 6;
  const int lane = threadIdx.x & 63;
  const int lr = lane & 15, lg = lane >> 4;
  const int rowA = mt + w * 32 + lr;

  // acc planes: 0=r, 1=z, 2=i_n (x part), 3=h_n (h part)
  f32x4 acc[4][2][2] = {};

  size_t xoff[2], hoff[2], woff[2];
  #pragma unroll
  for (int m = 0; m < 2; ++m) {
    xoff[m] = (size_t)(rowA + m * 16) * xstr;
    hoff[m] = (size_t)(rowA + m * 16) * Hsz;
  }
  #pragma unroll
  for (int nf = 0; nf < 2; ++nf) woff[nf] = (size_t)(nt + nf * 16 + lr) * Hsz;

  for (int k0 = 0; k0 < Hsz; k0 += 32) {
    const int ko = k0 + lg * 8;
    bf16x8 axh[2], axl[2], ahh[2], ahl[2];
    #pragma unroll
    for (int m = 0; m < 2; ++m) {
      axh[m] = ld8u(xh + xoff[m] + ko);
      axl[m] = ld8u(xl + xoff[m] + ko);
      ahh[m] = ld8u(hhi + hoff[m] + ko);
      ahl[m] = ld8u(hli + hoff[m] + ko);
    }
    #pragma unroll
    for (int p = 0; p < 3; ++p) {
      #pragma unroll
      for (int nf = 0; nf < 2; ++nf) {
        const size_t bo = woff[nf] + (size_t)p * Hsz * Hsz + ko;
        bf16x8 bih_h = ld8u(wihh + bo);
        bf16x8 bih_l = ld8u(wihl + bo);
        bf16x8 bhh_h = ld8u(whhh + bo);
        bf16x8 bhh_l = ld8u(whhl + bo);
        const int xi = (p == 2) ? 2 : p;
        const int hi_ = (p == 2) ? 3 : p;
        #pragma unroll
        for (int m = 0; m < 2; ++m) {
          acc[xi][m][nf]  = __builtin_amdgcn_mfma_f32_16x16x32_bf16(axh[m], bih_h, acc[xi][m][nf], 0, 0, 0);
          acc[xi][m][nf]  = __builtin_amdgcn_mfma_f32_16x16x32_bf16(axh[m], bih_l, acc[xi][m][nf], 0, 0, 0);
          acc[xi][m][nf]  = __builtin_amdgcn_mfma_f32_16x16x32_bf16(axl[m], bih_h, acc[xi][m][nf], 0, 0, 0);
          acc[hi_][m][nf] = __builtin_amdgcn_mfma_f32_16x16x32_bf16(ahh[m], bhh_h, acc[hi_][m][nf], 0, 0, 0);
          acc[hi_][m][nf] = __builtin_amdgcn_mfma_f32_16x16x32_bf16(ahh[m], bhh_l, acc[hi_][m][nf], 0, 0, 0);
          acc[hi_][m][nf] = __builtin_amdgcn_mfma_f32_16x16x32_bf16(ahl[m], bhh_h, acc[hi_][m][nf], 0, 0, 0);
        }
      }
    }
  }

  #pragma unroll
  for (int nf = 0; nf < 2; ++nf) {
    const int c = nt + nf * 16 + lr;
    const float br_i = bih[c],           br_h = bhh[c];
    const float bz_i = bih[Hsz + c],     bz_h = bhh[Hsz + c];
    const float bn_i = bih[2 * Hsz + c], bn_h = bhh[2 * Hsz + c];
    #pragma unroll
    for (int m = 0; m < 2; ++m) {
      #pragma unroll
      for (int r = 0; r < 4; ++r) {
        const int row = mt + w * 32 + m * 16 + lg * 4 + r;
        const size_t o = (size_t)row * Hsz + c;
        const float rr = 1.f / (1.f + expf(-(acc[0][m][nf][r] + br_i + br_h)));
        const float zz = 1.f / (1.f + expf(-(acc[1][m][nf][r] + bz_i + bz_h)));
        const float nn = tanhf(acc[2][m][nf][r] + bn_i + rr * (acc[3][m][nf][r] + bn_h));
        const float h = (1.f - zz) * nn + zz * hf_in[o];
        hf_out[o] = h;
        const unsigned short hb = f2bf(h);
        hho[o] = hb; hlo[o] = f2bf(h - bf2f(hb));
      }
    }
  }
}

// ---------------- q = h_new @ Wl_w^T + Wl_b (3-pass MFMA, fp32 out) ------------
__global__ __launch_bounds__(128) void k_q(
    const unsigned short* __restrict__ hhi, const unsigned short* __restrict__ hli,
    const unsigned short* __restrict__ wlh, const unsigned short* __restrict__ wll,
    const float* __restrict__ wlb, float* __restrict__ q)
{
  const int nt = blockIdx.x * 32;
  const int mt = blockIdx.y * 64;
  const int w = threadIdx.x >> 6;
  const int lane = threadIdx.x & 63;
  const int lr = lane & 15, lg = lane >> 4;
  const int rowA = mt + w * 32 + lr;

  f32x4 acc[2][2] = {};
  size_t hoff[2], woff[2];
  #pragma unroll
  for (int m = 0; m < 2; ++m) hoff[m] = (size_t)(rowA + m * 16) * Hsz;
  #pragma unroll
  for (int nf = 0; nf < 2; ++nf) woff[nf] = (size_t)(nt + nf * 16 + lr) * Hsz;

  for (int k0 = 0; k0 < Hsz; k0 += 32) {
    const int ko = k0 + lg * 8;
    bf16x8 ah[2], al[2];
    #pragma unroll
    for (int m = 0; m < 2; ++m) { ah[m] = ld8u(hhi + hoff[m] + ko); al[m] = ld8u(hli + hoff[m] + ko); }
    #pragma unroll
    for (int nf = 0; nf < 2; ++nf) {
      bf16x8 bh = ld8u(wlh + woff[nf] + ko);
      bf16x8 bl = ld8u(wll + woff[nf] + ko);
      #pragma unroll
      for (int m = 0; m < 2; ++m) {
        acc[m][nf] = __builtin_amdgcn_mfma_f32_16x16x32_bf16(ah[m], bh, acc[m][nf], 0, 0, 0);
        acc[m][nf] = __builtin_amdgcn_mfma_f32_16x16x32_bf16(ah[m], bl, acc[m][nf], 0, 0, 0);
        acc[m][nf] = __builtin_amdgcn_mfma_f32_16x16x32_bf16(al[m], bh, acc[m][nf], 0, 0, 0);
      }
    }
  }

  #pragma unroll
  for (int nf = 0; nf < 2; ++nf) {
    const int c = nt + nf * 16 + lr;
    const float bb = wlb[c];
    #pragma unroll
    for (int m = 0; m < 2; ++m) {
      #pragma unroll
      for (int r = 0; r < 4; ++r) {
        const int row = mt + w * 32 + m * 16 + lg * 4 + r;
        q[(size_t)row * Hsz + c] = acc[m][nf][r] + bb;
      }
    }
  }
}

// ---------------- attention scores + masked softmax + argmax/flag + outputs ----
__global__ __launch_bounds__(256) void k_attn(
    const float* __restrict__ q, const float* __restrict__ ih,
    unsigned int* __restrict__ flag, const unsigned int* __restrict__ valid,
    float* __restrict__ out, int t)
{
  const int b = blockIdx.x;
  __shared__ float pre_s[32];
  __shared__ float top_s[32];
  const int w = threadIdx.x >> 6;
  const int lane = threadIdx.x & 63;

  float qr[16];
  const float4* q4 = (const float4*)(q + (size_t)b * Hsz);
  #pragma unroll
  for (int i = 0; i < 4; ++i) {
    const float4 v = q4[lane * 4 + i];
    qr[4*i+0] = v.x; qr[4*i+1] = v.y; qr[4*i+2] = v.z; qr[4*i+3] = v.w;
  }

  for (int l = w; l < Lsz; l += 4) {
    const float4* r4 = (const float4*)(ih + (size_t)b * Lsz * Hsz + (size_t)l * Hsz);
    float s = 0.f;
    #pragma unroll
    for (int i = 0; i < 4; ++i) {
      const float4 v = r4[lane * 4 + i];
      s = fmaf(qr[4*i+0], v.x, s);
      s = fmaf(qr[4*i+1], v.y, s);
      s = fmaf(qr[4*i+2], v.z, s);
      s = fmaf(qr[4*i+3], v.w, s);
    }
    #pragma unroll
    for (int off = 32; off >= 1; off >>= 1) s += __shfl_xor(s, off, 64);
    if (lane == 0) pre_s[l] = s;
  }
  __syncthreads();

  if (threadIdx.x == 0) {
    const unsigned int fl = flag[b];
    const unsigned int ex = fl | ~valid[b];
    float best = -3.4e38f; int am = 0;
    for (int l = 0; l < Lsz; ++l) {
      if (!((ex >> l) & 1u)) { const float v = pre_s[l]; if (v > best) { best = v; am = l; } }
    }
    float sum = 0.f;
    for (int l = 0; l < Lsz; ++l) {
      const float e = ((ex >> l) & 1u) ? 0.f : expf(pre_s[l] - best);
      top_s[l] = e; sum += e;
    }
    const float inv = 1.f / sum;
    for (int l = 0; l < Lsz; ++l) top_s[l] *= inv;
    flag[b] = fl | (1u << am);
  }
  __syncthreads();

  if (threadIdx.x < Lsz) {
    const int l = threadIdx.x;
    out[(size_t)b * (Tsz * Lsz) + t * Lsz + l] = pre_s[l];
    out[(size_t)Bsz * Tsz * Lsz + (size_t)b * (Tsz * Lsz) + t * Lsz + l] = top_s[l];
  }
}

extern "C" void kernel_launch(void* const* d_in, const int* in_sizes, int n_in,
                              void* d_out, int out_size, void* d_ws, size_t ws_size,
                              hipStream_t stream) {
  const float* ih  = (const float*)d_in[0];
  const float* tg  = (const float*)d_in[1];
  const int*   pos = (const int*)d_in[2];
  const float* S   = (const float*)d_in[4];
  const float* wih = (const float*)d_in[5];
  const float* whh = (const float*)d_in[6];
  const float* bih = (const float*)d_in[7];
  const float* bhh = (const float*)d_in[8];
  const float* wlw = (const float*)d_in[9];
  const float* wlb = (const float*)d_in[10];
  float* out = (float*)d_out;

  char* p = (char*)d_ws;
  const size_t NX = (size_t)Bsz * Tsz * Hsz;     // 15.7M
  const size_t NW3 = (size_t)3 * Hsz * Hsz;      // 3.1M
  const size_t NW1 = (size_t)Hsz * Hsz;          // 1M
  const size_t NH = (size_t)Bsz * Hsz;           // 0.5M

  unsigned short* xh = (unsigned short*)p; p += NX * 2;
  unsigned short* xl = (unsigned short*)p; p += NX * 2;
  unsigned short* Sh = (unsigned short*)p; p += 2048;
  unsigned short* Sl = (unsigned short*)p; p += 2048;
  unsigned short* wihh = (unsigned short*)p; p += NW3 * 2;
  unsigned short* wihl = (unsigned short*)p; p += NW3 * 2;
  unsigned short* whhh = (unsigned short*)p; p += NW3 * 2;
  unsigned short* whhl = (unsigned short*)p; p += NW3 * 2;
  unsigned short* wlh = (unsigned short*)p; p += NW1 * 2;
  unsigned short* wll = (unsigned short*)p; p += NW1 * 2;
  float* hf0 = (float*)p; p += NH * 4;
  float* hf1 = (float*)p; p += NH * 4;
  unsigned short* hh0 = (unsigned short*)p; p += NH * 2;
  unsigned short* hl0 = (unsigned short*)p; p += NH * 2;
  unsigned short* hh1 = (unsigned short*)p; p += NH * 2;
  unsigned short* hl1 = (unsigned short*)p; p += NH * 2;
  float* q = (float*)p; p += NH * 4;
  unsigned int* flag  = (unsigned int*)p; p += Bsz * 4;
  unsigned int* valid = (unsigned int*)p; p += Bsz * 4;

  k_split<<<(int)(NX / 4 + 255) / 256, 256, 0, stream>>>(tg, xh, xl, (int)(NX / 4));
  k_split<<<1, 256, 0, stream>>>(S, Sh, Sl, Hsz / 4);
  k_split<<<(int)(NW3 / 4 + 255) / 256, 256, 0, stream>>>(wih, wihh, wihl, (int)(NW3 / 4));
  k_split<<<(int)(NW3 / 4 + 255) / 256, 256, 0, stream>>>(whh, whhh, whhl, (int)(NW3 / 4));
  k_split<<<(int)(NW1 / 4 + 255) / 256, 256, 0, stream>>>(wlw, wlh, wll, (int)(NW1 / 4));
  k_init<<<Bsz, 256, 0, stream>>>(ih, pos, hf0, hh0, hl0, flag, valid);

  for (int t = 0; t < Tsz; ++t) {
    const unsigned short* xhp = (t == 0) ? Sh : (xh + (size_t)(t - 1) * Hsz);
    const unsigned short* xlp = (t == 0) ? Sl : (xl + (size_t)(t - 1) * Hsz);
    const long xstr = (t == 0) ? 0L : (long)(Tsz * Hsz);
    const float* hfi = (t & 1) ? hf1 : hf0;
    float*       hfo = (t & 1) ? hf0 : hf1;
    const unsigned short* hhi = (t & 1) ? hh1 : hh0;
    const unsigned short* hli = (t & 1) ? hl1 : hl0;
    unsigned short* hho = (t & 1) ? hh0 : hh1;
    unsigned short* hlo = (t & 1) ? hl0 : hl1;

    k_gru<<<dim3(32, 8), 128, 0, stream>>>(xhp, xlp, xstr, hfi, hhi, hli,
                                           wihh, wihl, whhh, whhl, bih, bhh,
                                           hfo, hho, hlo);
    k_q<<<dim3(32, 8), 128, 0, stream>>>(hho, hlo, wlh, wll, wlb, q);
    k_attn<<<Bsz, 256, 0, stream>>>(q, ih, flag, valid, out, t);
  }
}